// Round 9
// baseline (105045.374 us; speedup 1.0000x reference)
//
#include <hip/hip_runtime.h>
#include <math.h>

#define NLAB   33
#define HD     512
#define NEQ    7
#define NSEQ   16385
#define TSTEPS 16384
#define MSIM   16384
#define GWG    32          // persistent workgroups in scan
#define CH     16          // hidden units per workgroup (512/32)
#define BTHR   512         // 8 waves; each wave owns 2 hidden units
#define SLOTS  4           // rotating mailbox depth (8 KB)
#define WCOL   34          // wemb_lds row stride: 33 labels + 1 personalized
#define NB1    4096        // term1 partial blocks
#define NB2    4096        // term2 partial blocks
#define CANARY 0xFFFFFFFFu // -NaN bit pattern; h is never NaN

__device__ __forceinline__ float sigmoid_(float x) { return 1.0f / (1.0f + __expf(-x)); }
__device__ __forceinline__ float softplus_(float x) { return fmaxf(x, 0.0f) + log1pf(__expf(-fabsf(x))); }
__device__ __forceinline__ float tanh_(float x) {
  float ax = fabsf(x);
  float e  = __expf(2.0f * ax);
  float t  = 1.0f - 2.0f / (e + 1.0f);
  return copysignf(t, x);
}

// ---------- precompute (d folded in):
//   WEmb[ij*33+l] = W[e,i,:].Emb[:,l] + d[ij]     (l<33)
//   WPers[ij]     = W[e,i,:].EmbP[:,sid] + d[ij]
__global__ void precompute_kernel(const float* __restrict__ W,
                                  const float* __restrict__ Emb,
                                  const float* __restrict__ EmbP,
                                  const int*   __restrict__ seq_id,
                                  const float* __restrict__ dvec,
                                  float* __restrict__ WEmb,
                                  float* __restrict__ WPers) {
  int idx = blockIdx.x * blockDim.x + threadIdx.x;
  const int total = NEQ * HD * (NLAB + 1);
  if (idx >= total) return;
  int l  = idx % (NLAB + 1);
  int ij = idx / (NLAB + 1);
  const float* Wrow = W + (size_t)ij * HD;
  float acc = dvec[ij];
  if (l < NLAB) {
    for (int k = 0; k < HD; ++k) acc = fmaf(Wrow[k], Emb[(size_t)k * NLAB + l], acc);
    WEmb[(size_t)ij * NLAB + l] = acc;
  } else {
    int sid = seq_id[0];
    for (int k = 0; k < HD; ++k) acc = fmaf(Wrow[k], EmbP[(size_t)k * 1024 + sid], acc);
    WPers[ij] = acc;
  }
}

// ---------- sequential scan: per-wave-complete units, single barrier per step,
// ---------- early-issued per-thread mailbox poll
__global__ __launch_bounds__(BTHR, 1) void scan_kernel(
    const int*   __restrict__ label_seq,
    const float* __restrict__ time_seq,
    const float* __restrict__ U,
    const float* __restrict__ WEmb,
    const float* __restrict__ WPers,
    float* __restrict__ mbox,       // [SLOTS][HD] rotating mailbox, pre-set to CANARY
    float* __restrict__ h_hist,
    float* __restrict__ c_hist,
    float* __restrict__ cb_hist,
    float* __restrict__ dl_hist,
    float* __restrict__ o_hist) {
  const int g   = blockIdx.x;
  const int tid = threadIdx.x;
  const int wv  = tid >> 6;         // wave 0..7
  const int l   = tid & 63;         // lane
  const int e   = l >> 3;           // equation 0..7 (valid <7)
  const int kg  = l & 7;            // K-split group: k in [kg*64, kg*64+64)
  const int ee  = (e < 7) ? e : 6;  // clamp for address validity (lanes 56-63 idle)

  const int uA = 2 * wv, uB = 2 * wv + 1;        // this wave's 2 local units
  const int jA = g * CH + uA, jB = g * CH + uB;  // global hidden indices

  // U rows (ee, jA) and (ee, jB), k-window kg*64.., float4 blocks permuted by
  // (b+kg)&15 — same permutation on the h LDS refill -> conflict-free.
  float u0[64], u1[64];
  {
    const float* Ur0 = U + ((size_t)ee * HD + jA) * HD + kg * 64;
    const float* Ur1 = U + ((size_t)ee * HD + jB) * HD + kg * 64;
#pragma unroll
    for (int b = 0; b < 16; ++b) {
      int cb = ((b + kg) & 15) * 4;
      float4 a = *(const float4*)(Ur0 + cb);
      u0[4*b+0] = a.x; u0[4*b+1] = a.y; u0[4*b+2] = a.z; u0[4*b+3] = a.w;
      float4 c = *(const float4*)(Ur1 + cb);
      u1[4*b+0] = c.x; u1[4*b+1] = c.y; u1[4*b+2] = c.z; u1[4*b+3] = c.w;
    }
  }

  __shared__ float h_lds[HD];
  __shared__ float wemb_lds[NEQ * CH * WCOL];   // [112][34]: 33 labels + pers, 15.2 KB
  for (int idx = tid; idx < NEQ * CH * WCOL; idx += BTHR) {
    int r = idx / WCOL, c = idx % WCOL;
    int re = r / CH, rj = r % CH;
    int ij = re * HD + g * CH + rj;
    wemb_lds[idx] = (c < NLAB) ? WEmb[(size_t)ij * NLAB + c] : WPers[ij];
  }

  float cA = 0.0f, cbA = 0.0f, cB = 0.0f, cbB = 0.0f;  // redundant in all lanes
  float hreg[64];
#pragma unroll
  for (int kk = 0; kk < 64; ++kk) hreg[kk] = 0.0f;
  float tp = time_seq[0];
  __syncthreads();

  for (int t = 0; t < TSTEPS; ++t) {
    const int slot = t & (SLOTS - 1);
    float* mrow = mbox + slot * HD;
    const bool more = (t + 1 < TSTEPS);
    const bool own  = ((tid >> 4) == g);

    // -- early poll issue: my mailbox word for THIS step's row (overlaps matvec)
    unsigned pv = CANARY;
    if (more && !own)
      pv = __hip_atomic_load((const unsigned*)&mrow[tid], __ATOMIC_RELAXED, __HIP_MEMORY_SCOPE_AGENT);

    const int lidx = (t > 0) ? label_seq[t] : NLAB;   // col 33 = personalized @ t=0
    const float tc = time_seq[t + 1];

    // -- partial matvec: 128 FMA per thread
    float acc0 = 0.0f, acc1 = 0.0f;
#pragma unroll
    for (int kk = 0; kk < 64; ++kk) {
      acc0 = fmaf(u0[kk], hreg[kk], acc0);
      acc1 = fmaf(u1[kk], hreg[kk], acc1);
    }
    // reduce across the 8 K-split lanes (stays within each e-group)
#pragma unroll
    for (int m = 1; m <= 4; m <<= 1) {
      acc0 += __shfl_xor(acc0, m, 64);
      acc1 += __shfl_xor(acc1, m, 64);
    }

    // -- gather the 7 equation temps in-wave; all lanes compute gates (uniform)
    float tAv[7], tBv[7];
#pragma unroll
    for (int q = 0; q < 7; ++q) {
      float a = __shfl(acc0, q * 8, 64);
      float b = __shfl(acc1, q * 8, 64);
      tAv[q] = a + wemb_lds[(q * CH + uA) * WCOL + lidx];
      tBv[q] = b + wemb_lds[(q * CH + uB) * WCOL + lidx];
    }
    const float dt = tc - tp;
    // unit A
    float i_gA = sigmoid_(tAv[0]), f_gA = sigmoid_(tAv[1]), zA = tanh_(tAv[2]);
    float oA = sigmoid_(tAv[3]), i2A = sigmoid_(tAv[4]), f2A = sigmoid_(tAv[5]);
    float dlA = softplus_(tAv[6]);
    float cnA  = f_gA * cA + i_gA * zA;
    float cbnA = f2A * cbA + i2A * zA;
    float cdA  = cbnA + (cnA - cbnA) * __expf(-dlA * dt);
    float hA   = oA * tanh_(cdA);
    cA = cdA; cbA = cbnA;
    // unit B
    float i_gB = sigmoid_(tBv[0]), f_gB = sigmoid_(tBv[1]), zB = tanh_(tBv[2]);
    float oB = sigmoid_(tBv[3]), i2B = sigmoid_(tBv[4]), f2B = sigmoid_(tBv[5]);
    float dlB = softplus_(tBv[6]);
    float cnB  = f_gB * cB + i_gB * zB;
    float cbnB = f2B * cbB + i2B * zB;
    float cdB  = cbnB + (cnB - cbnB) * __expf(-dlB * dt);
    float hB   = oB * tanh_(cdB);
    cB = cdB; cbB = cbnB;

    // -- publish (lanes 0/1 of each wave), fire-and-forget
    if (l == 0) {
      h_lds[jA] = hA;
      __hip_atomic_store((unsigned*)&mrow[jA], __float_as_uint(hA),
                         __ATOMIC_RELAXED, __HIP_MEMORY_SCOPE_AGENT);
      size_t off = (size_t)t * HD + jA;
      h_hist[off] = hA; c_hist[off] = cnA; cb_hist[off] = cbnA;
      dl_hist[off] = dlA; o_hist[off] = oA;
    } else if (l == 1) {
      h_lds[jB] = hB;
      __hip_atomic_store((unsigned*)&mrow[jB], __float_as_uint(hB),
                         __ATOMIC_RELAXED, __HIP_MEMORY_SCOPE_AGENT);
      size_t off = (size_t)t * HD + jB;
      h_hist[off] = hB; c_hist[off] = cnB; cb_hist[off] = cbnB;
      dl_hist[off] = dlB; o_hist[off] = oB;
    }

    // -- consume: own block resets the dead slot; others finish their 1-word poll
    if (more) {
      if (own) {
        if (t >= 2)   // slot (t-2)&3: all WGs done reading it (proved via t-1 publishes)
          __hip_atomic_store((unsigned*)&mbox[((t - 2) & (SLOTS - 1)) * HD + tid], CANARY,
                             __ATOMIC_RELAXED, __HIP_MEMORY_SCOPE_AGENT);
      } else {
        unsigned v = pv;
        while (v == CANARY)
          v = __hip_atomic_load((const unsigned*)&mrow[tid], __ATOMIC_RELAXED, __HIP_MEMORY_SCOPE_AGENT);
        h_lds[tid] = __uint_as_float(v);
      }
    }
    __syncthreads();   // h_lds complete; drains resets/publishes (vmcnt 0)

    // -- refill h fragment from LDS (permuted float4, conflict-free)
    if (more) {
#pragma unroll
      for (int b = 0; b < 16; ++b) {
        int cb = ((b + kg) & 15) * 4;            // same permutation as u0/u1
        float4 v = *(const float4*)&h_lds[kg * 64 + cb];
        hreg[4*b+0] = v.x; hreg[4*b+1] = v.y; hreg[4*b+2] = v.z; hreg[4*b+3] = v.w;
      }
    }
    tp = tc;
  }
}

// ---------- term1: sum over masked steps of log(lambda[t, TARGET-1]); one wave per step
__global__ void term1_kernel(const float* __restrict__ h_hist,
                             const float* __restrict__ wmat,
                             const int*   __restrict__ label_seq,
                             const float* __restrict__ log_s,
                             float* __restrict__ partial1) {
  int wid  = (blockIdx.x * blockDim.x + threadIdx.x) >> 6;
  int lane = threadIdx.x & 63;
  float lsum = 0.0f;
  if (wid < TSTEPS - 1) {
    const float* hr = h_hist + (size_t)wid * HD;
    float acc = 0.0f;
#pragma unroll
    for (int i = 0; i < 8; ++i) acc = fmaf(hr[lane * 8 + i], wmat[lane * 8 + i], acc);
#pragma unroll
    for (int m = 1; m < 64; m <<= 1) acc += __shfl_xor(acc, m, 64);
    if (lane == 0 && label_seq[wid + 1] == 1) {
      float s0  = __expf(log_s[0]);
      float lam = s0 * softplus_(acc / s0) + 1e-9f;
      lsum = __logf(lam);
    }
  }
  __shared__ float bsum[4];
  if (lane == 0) bsum[threadIdx.x >> 6] = lsum;
  __syncthreads();
  if (threadIdx.x == 0) partial1[blockIdx.x] = bsum[0] + bsum[1] + bsum[2] + bsum[3];
}

// ---------- term2: sum over sim points of lambda_sim[s, TARGET-1]; one wave per sim point
__global__ void term2_kernel(const float* __restrict__ c_hist,
                             const float* __restrict__ cb_hist,
                             const float* __restrict__ dl_hist,
                             const float* __restrict__ o_hist,
                             const float* __restrict__ wmat,
                             const float* __restrict__ log_s,
                             const int*   __restrict__ sim_idx,
                             const float* __restrict__ sim_time,
                             const float* __restrict__ time_seq,
                             float* __restrict__ partial2) {
  int wid  = (blockIdx.x * blockDim.x + threadIdx.x) >> 6;
  int lane = threadIdx.x & 63;
  float lsum = 0.0f;
  if (wid < MSIM) {
    int   idx = sim_idx[wid];
    float dts = sim_time[wid] - time_seq[idx];
    size_t off = (size_t)idx * HD + lane * 8;
    float acc = 0.0f;
#pragma unroll
    for (int i = 0; i < 8; ++i) {
      float cb = cb_hist[off + i];
      float c  = c_hist[off + i];
      float dl = dl_hist[off + i];
      float o  = o_hist[off + i];
      float cs = cb + (c - cb) * __expf(-dl * dts);
      float hs = o * tanh_(cs);
      acc = fmaf(hs, wmat[lane * 8 + i], acc);
    }
#pragma unroll
    for (int m = 1; m < 64; m <<= 1) acc += __shfl_xor(acc, m, 64);
    if (lane == 0) {
      float s0 = __expf(log_s[0]);
      lsum = s0 * softplus_(acc / s0) + 1e-9f;
    }
  }
  __shared__ float bsum[4];
  if (lane == 0) bsum[threadIdx.x >> 6] = lsum;
  __syncthreads();
  if (threadIdx.x == 0) partial2[blockIdx.x] = bsum[0] + bsum[1] + bsum[2] + bsum[3];
}

// ---------- final: deterministic reduction of partials, assemble output
__global__ void final_kernel(const float* __restrict__ partial1,
                             const float* __restrict__ partial2,
                             const float* __restrict__ time_seq,
                             float* __restrict__ out) {
  int lane = threadIdx.x;
  float s1 = 0.0f, s2 = 0.0f;
  for (int i = lane; i < NB1; i += 64) s1 += partial1[i];
  for (int i = lane; i < NB2; i += 64) s2 += partial2[i];
#pragma unroll
  for (int m = 1; m < 64; m <<= 1) {
    s1 += __shfl_xor(s1, m, 64);
    s2 += __shfl_xor(s2, m, 64);
  }
  if (lane == 0) {
    float term1 = s1;
    float term2 = (s2 / (float)MSIM) * (time_seq[NSEQ - 1] - time_seq[0]);
    out[0] = -(term1 - term2);
  }
}

extern "C" void kernel_launch(void* const* d_in, const int* in_sizes, int n_in,
                              void* d_out, int out_size, void* d_ws, size_t ws_size,
                              hipStream_t stream) {
  const int*   label_seq = (const int*)  d_in[0];
  const float* time_seq  = (const float*)d_in[1];
  const float* sim_time  = (const float*)d_in[2];
  const int*   sim_idx   = (const int*)  d_in[3];
  const int*   seq_id    = (const int*)  d_in[4];
  const float* Emb       = (const float*)d_in[5];
  const float* EmbP      = (const float*)d_in[6];
  const float* W         = (const float*)d_in[7];
  const float* U         = (const float*)d_in[8];
  const float* dvec      = (const float*)d_in[9];
  const float* wmat      = (const float*)d_in[10];
  const float* log_s     = (const float*)d_in[11];
  float* out = (float*)d_out;

  char* ws = (char*)d_ws;
  size_t off = 0;
  auto alloc = [&](size_t bytes) -> void* {
    void* p = ws + off;
    off += (bytes + 255) & ~(size_t)255;
    return p;
  };
  float*    WEmb     = (float*)   alloc((size_t)NEQ * HD * NLAB * 4);
  float*    WPers    = (float*)   alloc((size_t)NEQ * HD * 4);
  float*    mbox     = (float*)   alloc((size_t)SLOTS * HD * 4);
  float*    h_hist   = (float*)   alloc((size_t)TSTEPS * HD * 4);
  float*    c_hist   = (float*)   alloc((size_t)TSTEPS * HD * 4);
  float*    cb_hist  = (float*)   alloc((size_t)TSTEPS * HD * 4);
  float*    dl_hist  = (float*)   alloc((size_t)TSTEPS * HD * 4);
  float*    o_hist   = (float*)   alloc((size_t)TSTEPS * HD * 4);
  float*    partial1 = (float*)   alloc((size_t)NB1 * 4);
  float*    partial2 = (float*)   alloc((size_t)NB2 * 4);
  (void)ws_size; (void)in_sizes; (void)n_in; (void)out_size;

  // rotating mailbox must be all-canary at scan start on every replay (8 KB)
  hipMemsetAsync(mbox, 0xFF, (size_t)SLOTS * HD * 4, stream);

  {
    int total  = NEQ * HD * (NLAB + 1);
    int blocks = (total + 255) / 256;
    precompute_kernel<<<blocks, 256, 0, stream>>>(W, Emb, EmbP, seq_id, dvec, WEmb, WPers);
  }
  scan_kernel<<<GWG, BTHR, 0, stream>>>(label_seq, time_seq, U, WEmb, WPers,
                                        mbox, h_hist, c_hist, cb_hist, dl_hist, o_hist);
  term1_kernel<<<NB1, 256, 0, stream>>>(h_hist, wmat, label_seq, log_s, partial1);
  term2_kernel<<<NB2, 256, 0, stream>>>(c_hist, cb_hist, dl_hist, o_hist, wmat, log_s,
                                        sim_idx, sim_time, time_seq, partial2);
  final_kernel<<<1, 64, 0, stream>>>(partial1, partial2, time_seq, out);
}

// Round 10
// 39856.015 us; speedup vs baseline: 2.6356x; 2.6356x over previous
//
#include <hip/hip_runtime.h>
#include <math.h>

#define NLAB   33
#define HD     512
#define NEQ    7
#define NSEQ   16385
#define TSTEPS 16384
#define MSIM   16384
#define GWG    32          // scan workgroups
#define NHEAT  224         // heater workgroups (keep clocks up); total 256 WGs
#define CH     16          // hidden units per scan WG (512/32)
#define RROWS  (NEQ*CH)    // 112 matvec rows per WG
#define BTHR   512         // threads per WG (8 waves), 2 row-slots/thread
#define SLOTS  4           // rotating mailbox depth
#define MBLK   32          // floats per mailbox block: 16 payload + 16 pad = one 128B line
#define MROWW  (GWG*MBLK)  // floats per mailbox slot row (32 blocks)
#define NB1    4096        // term1 partial blocks
#define NB2    4096        // term2 partial blocks
#define CANARY 0xFFFFFFFFu // -NaN bit pattern; h is never NaN

__device__ __forceinline__ float sigmoid_(float x) { return 1.0f / (1.0f + __expf(-x)); }
__device__ __forceinline__ float softplus_(float x) { return fmaxf(x, 0.0f) + log1pf(__expf(-fabsf(x))); }
__device__ __forceinline__ float tanh_(float x) {
  float ax = fabsf(x);
  float e  = __expf(2.0f * ax);
  float t  = 1.0f - 2.0f / (e + 1.0f);
  return copysignf(t, x);
}

// ---------- precompute: WEmb[e,i,l] = W[e,i,:].Emb[:,l]   (l<33)
//                        WPers[e,i]  = W[e,i,:].EmbP[:,sid] (l==33)
__global__ void precompute_kernel(const float* __restrict__ W,
                                  const float* __restrict__ Emb,
                                  const float* __restrict__ EmbP,
                                  const int*   __restrict__ seq_id,
                                  float* __restrict__ WEmb,
                                  float* __restrict__ WPers) {
  int idx = blockIdx.x * blockDim.x + threadIdx.x;
  const int total = NEQ * HD * (NLAB + 1);
  if (idx >= total) return;
  int l  = idx % (NLAB + 1);
  int ij = idx / (NLAB + 1);
  const float* Wrow = W + (size_t)ij * HD;
  float acc = 0.0f;
  if (l < NLAB) {
    for (int k = 0; k < HD; ++k) acc = fmaf(Wrow[k], Emb[(size_t)k * NLAB + l], acc);
    WEmb[(size_t)ij * NLAB + l] = acc;
  } else {
    int sid = seq_id[0];
    for (int k = 0; k < HD; ++k) acc = fmaf(Wrow[k], EmbP[(size_t)k * 1024 + sid], acc);
    WPers[ij] = acc;
  }
}

// ---------- scan (blocks 0..31) + heater (blocks 32..255)
__global__ __launch_bounds__(BTHR, 1) void scan_kernel(
    const int*   __restrict__ label_seq,
    const float* __restrict__ time_seq,
    const float* __restrict__ U,
    const float* __restrict__ dvec,
    const float* __restrict__ WEmb,
    const float* __restrict__ WPers,
    float* __restrict__ mbox,       // [SLOTS][GWG][MBLK], one 128B line per producer
    float* __restrict__ h_hist,
    float* __restrict__ c_hist,
    float* __restrict__ cb_hist,
    float* __restrict__ dl_hist,
    float* __restrict__ o_hist,
    unsigned* __restrict__ done) {
  const int g   = blockIdx.x;
  const int tid = threadIdx.x;

  if (g >= GWG) {
    // ---- heater: pure-register FMA spin, no memory traffic, exit on done flag.
    float a = 1.000001f, b = 0.999999f, c = (float)(tid + g);
    for (;;) {
#pragma unroll 16
      for (int i = 0; i < 4096; ++i) c = fmaf(a, c, b);
      asm volatile("" :: "v"(c));   // keep the loop alive
      if (__hip_atomic_load(done, __ATOMIC_RELAXED, __HIP_MEMORY_SCOPE_AGENT)) return;
    }
  }

  const int kg  = tid & 7;    // K-split group: k in [kg*64, kg*64+64)
  const int rs  = tid >> 3;   // row slot 0..63

  const int  r0  = rs;        // row 0..63
  const int  r1  = rs + 64;   // row 64..127; valid < RROWS (112)
  const bool v1  = (r1 < RROWS);
  const int  e0  = r0 / CH, jj0 = r0 % CH;
  const int  e1  = v1 ? (r1 / CH) : 0, jj1 = v1 ? (r1 % CH) : 0;
  const int  jg0 = g * CH + jj0, jg1 = g * CH + jj1;

  // U slices in registers, k-columns permuted by (b+kg)&15 per float4 block.
  // The same permutation is applied to the h LDS reads -> conflict-free, pairing preserved.
  float u0[64], u1[64];
  {
    const float* Ur0 = U + ((size_t)e0 * HD + jg0) * HD + kg * 64;
    const float* Ur1 = U + ((size_t)e1 * HD + jg1) * HD + kg * 64;
#pragma unroll
    for (int b = 0; b < 16; ++b) {
      int cb = ((b + kg) & 15) * 4;
      float4 a = *(const float4*)(Ur0 + cb);
      u0[4*b+0] = a.x; u0[4*b+1] = a.y; u0[4*b+2] = a.z; u0[4*b+3] = a.w;
      float4 c = *(const float4*)(Ur1 + cb);
      u1[4*b+0] = c.x; u1[4*b+1] = c.y; u1[4*b+2] = c.z; u1[4*b+3] = c.w;
    }
  }
  const float d0 = dvec[e0 * HD + jg0];
  const float d1 = dvec[e1 * HD + jg1];

  __shared__ float h_lds[HD];
  __shared__ float temp_lds[NEQ][CH];
  __shared__ float wemb_lds[RROWS * NLAB];   // this WG's W@Emb slice, 14.8 KB
  for (int idx = tid; idx < RROWS * NLAB; idx += BTHR) {
    int rr = idx / NLAB, l = idx % NLAB;
    int e = rr / CH, jj = rr % CH;
    wemb_lds[idx] = WEmb[((size_t)e * HD + g * CH + jj) * NLAB + l];
  }

  float c_reg = 0.0f, cb_reg = 0.0f;   // live in lanes tid<16 (wave 0)
  float hreg[64];
#pragma unroll
  for (int kk = 0; kk < 64; ++kk) hreg[kk] = 0.0f;
  __syncthreads();

  for (int t = 0; t < TSTEPS; ++t) {
    // -- W@lab gather (only the kg==0 writer lanes need it)
    float wl0 = 0.0f, wl1 = 0.0f;
    if (kg == 0) {
      if (t > 0) {
        int lab = label_seq[t];
        wl0 = wemb_lds[r0 * NLAB + lab];
        if (v1) wl1 = wemb_lds[r1 * NLAB + lab];
      } else {
        wl0 = WPers[e0 * HD + jg0];
        if (v1) wl1 = WPers[e1 * HD + jg1];
      }
    }
    float tp = 0.0f, tc = 0.0f;
    if (tid < CH) { tp = time_seq[t]; tc = time_seq[t + 1]; }

    // -- partial matvec: 128 FMA per thread, U and h both in regs
    float acc0 = 0.0f, acc1 = 0.0f;
#pragma unroll
    for (int kk = 0; kk < 64; ++kk) {
      acc0 = fmaf(u0[kk], hreg[kk], acc0);
      acc1 = fmaf(u1[kk], hreg[kk], acc1);
    }
    // reduce across the 8 K-split lanes (low 3 lane bits)
#pragma unroll
    for (int m = 1; m <= 4; m <<= 1) {
      acc0 += __shfl_xor(acc0, m, 64);
      acc1 += __shfl_xor(acc1, m, 64);
    }
    if (kg == 0) {
      temp_lds[e0][jj0] = acc0 + d0 + wl0;
      if (v1) temp_lds[e1][jj1] = acc1 + d1 + wl1;
    }
    __syncthreads();   // barrier 1: temps ready

    const int slot = t & (SLOTS - 1);
    float* mrow = mbox + slot * MROWW;

    // -- wave 0: gates + own-block LDS write + mailbox/history publish
    if (tid < 64) {
      if (tid < CH) {
        int j = tid, jgl = g * CH + j;
        float i_g = sigmoid_(temp_lds[0][j]);
        float f_g = sigmoid_(temp_lds[1][j]);
        float z   = tanh_(temp_lds[2][j]);
        float o   = sigmoid_(temp_lds[3][j]);
        float i2  = sigmoid_(temp_lds[4][j]);
        float f2  = sigmoid_(temp_lds[5][j]);
        float dl  = softplus_(temp_lds[6][j]);
        float cn  = f_g * c_reg + i_g * z;        // all_c[t]  (pre-decay)
        float cbn = f2 * cb_reg + i2 * z;         // all_cb[t]
        float ef  = __expf(-dl * (tc - tp));
        float cd  = cbn + (cn - cbn) * ef;        // carried c_t
        float h   = o * tanh_(cd);                // all_h[t]
        c_reg  = cd;
        cb_reg = cbn;
        h_lds[jgl] = h;                           // own block: no round trip
        // mailbox publish into this WG's PRIVATE 128B line (no false sharing)
        __hip_atomic_store((unsigned*)&mrow[g * MBLK + j], __float_as_uint(h),
                           __ATOMIC_RELAXED, __HIP_MEMORY_SCOPE_AGENT);
        size_t off = (size_t)t * HD + jgl;
        h_hist[off]  = h;
        c_hist[off]  = cn;
        cb_hist[off] = cbn;
        dl_hist[off] = dl;
        o_hist[off]  = o;
      }
    } else if (tid < 128 && t + 1 < TSTEPS) {
      // -- wave 1: reset dead slot / poll other blocks (2 lanes per block)
      const int lane = tid - 64;                  // 0..63
      const int b    = lane >> 1;                 // block 0..31
      const int hh   = lane & 1;                  // half: words [hh*8, hh*8+8) of payload
      if (b == g) {
        // own-block pair: canary-reset slot (t-2) instead of polling
        if (t >= 2) {
          unsigned long long* dead =
              (unsigned long long*)(mbox + ((t - 2) & (SLOTS - 1)) * MROWW + g * MBLK + hh * 8);
#pragma unroll
          for (int i = 0; i < 4; ++i)
            __hip_atomic_store(&dead[i], 0xFFFFFFFFFFFFFFFFull,
                               __ATOMIC_RELAXED, __HIP_MEMORY_SCOPE_AGENT);
        }
      } else {
        const unsigned long long* mb =
            (const unsigned long long*)(mrow + b * MBLK + hh * 8);
        unsigned long long q[4];
        bool ok;
        do {
#pragma unroll
          for (int i = 0; i < 4; ++i)
            q[i] = __hip_atomic_load(&mb[i], __ATOMIC_RELAXED, __HIP_MEMORY_SCOPE_AGENT);
          ok = true;
#pragma unroll
          for (int i = 0; i < 4; ++i)
            ok = ok && ((unsigned)q[i] != CANARY) && ((unsigned)(q[i] >> 32) != CANARY);
        } while (!ok);
#pragma unroll
        for (int i = 0; i < 4; ++i) {
          h_lds[b * CH + hh * 8 + 2*i + 0] = __uint_as_float((unsigned)q[i]);
          h_lds[b * CH + hh * 8 + 2*i + 1] = __uint_as_float((unsigned)(q[i] >> 32));
        }
      }
    }
    __syncthreads();   // barrier 2: h_lds complete

    // -- all threads: refill h fragment from LDS (permuted float4, conflict-free)
    if (t + 1 < TSTEPS) {
#pragma unroll
      for (int b = 0; b < 16; ++b) {
        int cb = ((b + kg) & 15) * 4;            // same permutation as u0/u1
        float4 v = *(const float4*)&h_lds[kg * 64 + cb];
        hreg[4*b+0] = v.x; hreg[4*b+1] = v.y; hreg[4*b+2] = v.z; hreg[4*b+3] = v.w;
      }
    }
  }

  // scan complete: release the heaters
  if (tid == 0)
    __hip_atomic_store(done, 1u, __ATOMIC_RELAXED, __HIP_MEMORY_SCOPE_AGENT);
}

// ---------- term1: sum over masked steps of log(lambda[t, TARGET-1]); one wave per step
__global__ void term1_kernel(const float* __restrict__ h_hist,
                             const float* __restrict__ wmat,
                             const int*   __restrict__ label_seq,
                             const float* __restrict__ log_s,
                             float* __restrict__ partial1) {
  int wid  = (blockIdx.x * blockDim.x + threadIdx.x) >> 6;
  int lane = threadIdx.x & 63;
  float lsum = 0.0f;
  if (wid < TSTEPS - 1) {
    const float* hr = h_hist + (size_t)wid * HD;
    float acc = 0.0f;
#pragma unroll
    for (int i = 0; i < 8; ++i) acc = fmaf(hr[lane * 8 + i], wmat[lane * 8 + i], acc);
#pragma unroll
    for (int m = 1; m < 64; m <<= 1) acc += __shfl_xor(acc, m, 64);
    if (lane == 0 && label_seq[wid + 1] == 1) {
      float s0  = __expf(log_s[0]);
      float lam = s0 * softplus_(acc / s0) + 1e-9f;
      lsum = __logf(lam);
    }
  }
  __shared__ float bsum[4];
  if (lane == 0) bsum[threadIdx.x >> 6] = lsum;
  __syncthreads();
  if (threadIdx.x == 0) partial1[blockIdx.x] = bsum[0] + bsum[1] + bsum[2] + bsum[3];
}

// ---------- term2: sum over sim points of lambda_sim[s, TARGET-1]; one wave per sim point
__global__ void term2_kernel(const float* __restrict__ c_hist,
                             const float* __restrict__ cb_hist,
                             const float* __restrict__ dl_hist,
                             const float* __restrict__ o_hist,
                             const float* __restrict__ wmat,
                             const float* __restrict__ log_s,
                             const int*   __restrict__ sim_idx,
                             const float* __restrict__ sim_time,
                             const float* __restrict__ time_seq,
                             float* __restrict__ partial2) {
  int wid  = (blockIdx.x * blockDim.x + threadIdx.x) >> 6;
  int lane = threadIdx.x & 63;
  float lsum = 0.0f;
  if (wid < MSIM) {
    int   idx = sim_idx[wid];
    float dts = sim_time[wid] - time_seq[idx];
    size_t off = (size_t)idx * HD + lane * 8;
    float acc = 0.0f;
#pragma unroll
    for (int i = 0; i < 8; ++i) {
      float cb = cb_hist[off + i];
      float c  = c_hist[off + i];
      float dl = dl_hist[off + i];
      float o  = o_hist[off + i];
      float cs = cb + (c - cb) * __expf(-dl * dts);
      float hs = o * tanh_(cs);
      acc = fmaf(hs, wmat[lane * 8 + i], acc);
    }
#pragma unroll
    for (int m = 1; m < 64; m <<= 1) acc += __shfl_xor(acc, m, 64);
    if (lane == 0) {
      float s0 = __expf(log_s[0]);
      lsum = s0 * softplus_(acc / s0) + 1e-9f;
    }
  }
  __shared__ float bsum[4];
  if (lane == 0) bsum[threadIdx.x >> 6] = lsum;
  __syncthreads();
  if (threadIdx.x == 0) partial2[blockIdx.x] = bsum[0] + bsum[1] + bsum[2] + bsum[3];
}

// ---------- final: deterministic reduction of partials, assemble output
__global__ void final_kernel(const float* __restrict__ partial1,
                             const float* __restrict__ partial2,
                             const float* __restrict__ time_seq,
                             float* __restrict__ out) {
  int lane = threadIdx.x;
  float s1 = 0.0f, s2 = 0.0f;
  for (int i = lane; i < NB1; i += 64) s1 += partial1[i];
  for (int i = lane; i < NB2; i += 64) s2 += partial2[i];
#pragma unroll
  for (int m = 1; m < 64; m <<= 1) {
    s1 += __shfl_xor(s1, m, 64);
    s2 += __shfl_xor(s2, m, 64);
  }
  if (lane == 0) {
    float term1 = s1;
    float term2 = (s2 / (float)MSIM) * (time_seq[NSEQ - 1] - time_seq[0]);
    out[0] = -(term1 - term2);
  }
}

extern "C" void kernel_launch(void* const* d_in, const int* in_sizes, int n_in,
                              void* d_out, int out_size, void* d_ws, size_t ws_size,
                              hipStream_t stream) {
  const int*   label_seq = (const int*)  d_in[0];
  const float* time_seq  = (const float*)d_in[1];
  const float* sim_time  = (const float*)d_in[2];
  const int*   sim_idx   = (const int*)  d_in[3];
  const int*   seq_id    = (const int*)  d_in[4];
  const float* Emb       = (const float*)d_in[5];
  const float* EmbP      = (const float*)d_in[6];
  const float* W         = (const float*)d_in[7];
  const float* U         = (const float*)d_in[8];
  const float* dvec      = (const float*)d_in[9];
  const float* wmat      = (const float*)d_in[10];
  const float* log_s     = (const float*)d_in[11];
  float* out = (float*)d_out;

  char* ws = (char*)d_ws;
  size_t off = 0;
  auto alloc = [&](size_t bytes) -> void* {
    void* p = ws + off;
    off += (bytes + 255) & ~(size_t)255;
    return p;
  };
  float*    WEmb     = (float*)   alloc((size_t)NEQ * HD * NLAB * 4);
  float*    WPers    = (float*)   alloc((size_t)NEQ * HD * 4);
  float*    mbox     = (float*)   alloc((size_t)SLOTS * MROWW * 4);
  unsigned* done     = (unsigned*)alloc(256);
  float*    h_hist   = (float*)   alloc((size_t)TSTEPS * HD * 4);
  float*    c_hist   = (float*)   alloc((size_t)TSTEPS * HD * 4);
  float*    cb_hist  = (float*)   alloc((size_t)TSTEPS * HD * 4);
  float*    dl_hist  = (float*)   alloc((size_t)TSTEPS * HD * 4);
  float*    o_hist   = (float*)   alloc((size_t)TSTEPS * HD * 4);
  float*    partial1 = (float*)   alloc((size_t)NB1 * 4);
  float*    partial2 = (float*)   alloc((size_t)NB2 * 4);
  (void)ws_size; (void)in_sizes; (void)n_in; (void)out_size;

  // rotating mailbox all-canary + done flag cleared, every replay (16 KB)
  hipMemsetAsync(mbox, 0xFF, (size_t)SLOTS * MROWW * 4, stream);
  hipMemsetAsync(done, 0, 256, stream);

  {
    int total  = NEQ * HD * (NLAB + 1);
    int blocks = (total + 255) / 256;
    precompute_kernel<<<blocks, 256, 0, stream>>>(W, Emb, EmbP, seq_id, WEmb, WPers);
  }
  scan_kernel<<<GWG + NHEAT, BTHR, 0, stream>>>(label_seq, time_seq, U, dvec, WEmb, WPers,
                                                mbox, h_hist, c_hist, cb_hist, dl_hist,
                                                o_hist, done);
  term1_kernel<<<NB1, 256, 0, stream>>>(h_hist, wmat, label_seq, log_s, partial1);
  term2_kernel<<<NB2, 256, 0, stream>>>(c_hist, cb_hist, dl_hist, o_hist, wmat, log_s,
                                        sim_idx, sim_time, time_seq, partial2);
  final_kernel<<<1, 64, 0, stream>>>(partial1, partial2, time_seq, out);
}